// Round 9
// baseline (76.775 us; speedup 1.0000x reference)
//
#include <hip/hip_runtime.h>
#include <hip/hip_bf16.h>

typedef __attribute__((ext_vector_type(8))) short        short8;
typedef __attribute__((ext_vector_type(8))) __bf16       bf16x8;
typedef __attribute__((ext_vector_type(4))) float        f32x4;
typedef __attribute__((ext_vector_type(2))) unsigned int u32x2;

#define NB 32
#define CI 64
#define H  128
#define W  128
#define OH 126
#define OW 126
#define HW (H*W)

// bf16 LDS tile, ONE ci-half (32 channels): [pix = r*66+col][32 ci]
// RSTRIDE = 80 B/pix (64 B data + 16 B pad). 80 = 5*16: b128 reads stay
// 16B-aligned, and start quads (5*pix + hi) mod 8 cycle all 8 -> 2-way = free.
#define TCOLS 66
#define RSTRIDE 80
#define LDS_BYTES (6*TCOLS*RSTRIDE)   // 31680 B -> 5 blocks/CU

__device__ __forceinline__ unsigned int f2bf(float f) {
    unsigned int u = __builtin_bit_cast(unsigned int, f);
    u += 0x7fffu + ((u >> 16) & 1u);
    return u >> 16;
}

// packed f32x2 -> bf16x2 (RNE), 1 instruction
__device__ __forceinline__ unsigned int cvt_pk(float lo, float hi) {
    unsigned int r;
    asm("v_cvt_pk_bf16_f32 %0, %1, %2" : "=v"(r) : "v"(lo), "v"(hi));
    return r;
}

// tanh(x) = 1 - 2/(exp2(2*log2e*x)+1); exact at +/-inf, ~1e-7 abs err
__device__ __forceinline__ float fast_tanh(float x) {
    float e = __builtin_amdgcn_exp2f(x * 2.8853900817779268f);
    float r = __builtin_amdgcn_rcpf(e + 1.0f);
    return 1.0f - 2.0f * r;
}

// ---------------------------------------------------------------------------
// Pre-pass: weights (64,64,3,3) fp32 OIHW -> MFMA B-fragment order, bf16.
// flat elem idx = ((ks*4 + cf)*64 + lane)*8 + j
//   ks = 0..17: khw = ks>>1, ci-half = ks&1; cf = co quarter,
//   lane: co = cf*16 + (lane&15), ci = (ks&1)*32 + 8*(lane>>4) + j
// ---------------------------------------------------------------------------
__global__ void wxform(const float* __restrict__ w, unsigned short* __restrict__ ws) {
    int tid = blockIdx.x * 256 + threadIdx.x;
    if (tid >= 18*4*64*8) return;
    int j   = tid & 7;
    int l   = (tid >> 3) & 63;
    int cf  = (tid >> 9) & 3;
    int ks  = tid >> 11;
    int co  = cf*16 + (l & 15);
    int ci  = (ks & 1)*32 + ((l >> 4) << 3) + j;
    int khw = ks >> 1;               // kh*3+kw
    int kh  = khw / 3, kw = khw % 3;
    float v = w[co*(CI*9) + ci*9 + kh*3 + kw];
    ws[tid] = (unsigned short)f2bf(v);
}

// ---------------------------------------------------------------------------
// Main: implicit-GEMM conv + channel-min + tanh(tanh()).
// r1-6-proven staging (reg loads + cvt_pk + ds_write, zero-fill OOB) +
// ONE new element: two ci-half passes restaging a 31.7 KB buffer
// -> 5 blocks/CU (was 3). Bisects the r7/r8 failure AND lifts occupancy.
// ---------------------------------------------------------------------------
__global__ __launch_bounds__(256, 4)
void conv_min_tanh(const float* __restrict__ x,
                   const unsigned short* __restrict__ wfrag,
                   const float* __restrict__ bias,
                   float* __restrict__ out) {
    __shared__ __align__(16) char xs[LDS_BYTES];

    const int lane = threadIdx.x & 63;
    const int wv   = threadIdx.x >> 6;
    const int c0   = blockIdx.x * 64;   // ow base (0 or 64)
    const int r0   = blockIdx.y * 4;    // oh base
    const int b    = blockIdx.z;
    const float* xb = x + (size_t)b * CI * HW;

    const int lane_c = lane & 15;
    const int hi     = lane >> 4;

    const short8* wp = (const short8*)wfrag;
    const int orow = r0 + wv;
    const bool live = (orow < OH);       // wave-uniform

    f32x4 acc[4][4];
    #pragma unroll
    for (int m = 0; m < 4; ++m)
        #pragma unroll
        for (int cf = 0; cf < 4; ++cf)
            acc[m][cf] = (f32x4){0.f, 0.f, 0.f, 0.f};

    // A-read bases per khw (LDS addresses identical both passes):
    //   byte = ((wv+kh)*66 + lane_c + kw)*80 + hi*16, m-step = +16*80
    int abase[9];
    #pragma unroll
    for (int kh = 0; kh < 3; ++kh)
        #pragma unroll
        for (int kw = 0; kw < 3; ++kw)
            abase[kh*3 + kw] = ((wv + kh)*TCOLS + lane_c + kw)*RSTRIDE + hi*16;

    #pragma unroll
    for (int cih = 0; cih < 2; ++cih) {
        // ---------------- stage half cih (r6-style reg staging) ----------------
        // main: 48 tasks = (row 0..5) x (ci-quad 0..7); lane = col 0..63
        #pragma unroll
        for (int i = 0; i < 12; ++i) {
            const int tsk = wv + 4*i;           // 0..47
            const int r   = tsk >> 3;           // 0..5
            const int q   = tsk & 7;            // ci quad within half
            const int gr  = r0 + r;
            float v0=0.f, v1=0.f, v2=0.f, v3=0.f;
            if (gr < H) {                        // wave-uniform; zero-fill OOB
                const float* xp = xb + (size_t)(cih*32 + q*4)*HW + gr*W + c0 + lane;
                v0 = xp[0]; v1 = xp[HW]; v2 = xp[2*HW]; v3 = xp[3*HW];
            }
            u32x2 pk; pk.x = cvt_pk(v0, v1); pk.y = cvt_pk(v2, v3);
            *(u32x2*)(xs + (r*TCOLS + lane)*RSTRIDE + q*8) = pk;
        }
        // halo cols 64,65: threads 0..95 -> (row 0..5) x (col 2) x (quad 8)
        if (threadIdx.x < 96) {
            const int r   = threadIdx.x >> 4;    // 0..5
            const int sub = threadIdx.x & 15;
            const int cc  = sub & 1;
            const int q   = sub >> 1;            // 0..7
            const int gr  = r0 + r;
            const int gc  = c0 + 64 + cc;
            float v0=0.f, v1=0.f, v2=0.f, v3=0.f;
            if (gr < H && gc < W) {              // zero-fill OOB
                const float* xq = xb + (size_t)(cih*32 + q*4)*HW + gr*W + gc;
                v0 = xq[0]; v1 = xq[HW]; v2 = xq[2*HW]; v3 = xq[3*HW];
            }
            u32x2 pk; pk.x = cvt_pk(v0, v1); pk.y = cvt_pk(v2, v3);
            *(u32x2*)(xs + (r*TCOLS + 64 + cc)*RSTRIDE + q*8) = pk;
        }
        __syncthreads();

        // ---------------- compute half cih ----------------
        if (live) {
            short8 wfb[2][4];
            #pragma unroll
            for (int cf = 0; cf < 4; ++cf)       // ks = khw*2+cih with khw=0
                wfb[0][cf] = wp[(cih*4 + cf)*64 + lane];
            #pragma unroll
            for (int khw = 0; khw < 9; ++khw) {
                const int buf = khw & 1;
                if (khw < 8) {                   // prefetch next khw
                    #pragma unroll
                    for (int cf = 0; cf < 4; ++cf)
                        wfb[buf^1][cf] = wp[(((khw+1)*2 + cih)*4 + cf)*64 + lane];
                }
                #pragma unroll
                for (int m = 0; m < 4; ++m) {
                    const short8 av = *(const short8*)(xs + abase[khw] + m*(16*RSTRIDE));
                    const bf16x8 a = __builtin_bit_cast(bf16x8, av);
                    #pragma unroll
                    for (int cf = 0; cf < 4; ++cf)
                        acc[m][cf] = __builtin_amdgcn_mfma_f32_16x16x32_bf16(
                            a, __builtin_bit_cast(bf16x8, wfb[buf][cf]), acc[m][cf], 0, 0, 0);
                }
            }
        }
        if (cih == 0) __syncthreads();   // all reads done before restage
    }

    if (!live) return;

    // ---- epilogue: +bias, min over 64 co, tanh(tanh()), store ----
    const float bs0 = bias[lane_c], bs1 = bias[16 + lane_c],
                bs2 = bias[32 + lane_c], bs3 = bias[48 + lane_c];
    float* outp = out + (b*OH + orow)*OW;
    #pragma unroll
    for (int m = 0; m < 4; ++m) {
        #pragma unroll
        for (int rg = 0; rg < 4; ++rg) {
            float v0 = fminf(fminf(acc[m][0][rg] + bs0, acc[m][1][rg] + bs1),
                             fminf(acc[m][2][rg] + bs2, acc[m][3][rg] + bs3));
            v0 = fminf(v0, __shfl_xor(v0, 1));
            v0 = fminf(v0, __shfl_xor(v0, 2));
            v0 = fminf(v0, __shfl_xor(v0, 4));
            v0 = fminf(v0, __shfl_xor(v0, 8));
            const float vt = fast_tanh(fast_tanh(v0));
            const int ocol = c0 + m*16 + hi*4 + rg;
            if (lane_c == 0 && ocol < OW) outp[ocol] = vt;
        }
    }
}

extern "C" void kernel_launch(void* const* d_in, const int* in_sizes, int n_in,
                              void* d_out, int out_size, void* d_ws, size_t ws_size,
                              hipStream_t stream) {
    const float* x    = (const float*)d_in[0];
    const float* w    = (const float*)d_in[1];
    const float* bias = (const float*)d_in[2];
    float* out        = (float*)d_out;
    unsigned short* wbuf = (unsigned short*)d_ws;   // needs 73728 B

    wxform<<<dim3(144), dim3(256), 0, stream>>>(w, wbuf);
    conv_min_tanh<<<dim3(2, 32, NB), dim3(256), 0, stream>>>(x, wbuf, bias, out);
}

// Round 10
// 73.009 us; speedup vs baseline: 1.0516x; 1.0516x over previous
//
#include <hip/hip_runtime.h>
#include <hip/hip_bf16.h>

typedef __attribute__((ext_vector_type(8))) short        short8;
typedef __attribute__((ext_vector_type(8))) __bf16       bf16x8;
typedef __attribute__((ext_vector_type(4))) float        f32x4;
typedef __attribute__((ext_vector_type(4))) unsigned int u32x4;

#define NB 32
#define CI 64
#define H  128
#define W  128
#define OH 126
#define OW 126
#define HW (H*W)

// bf16 LDS tile, ONE ci-half (32 channels): [pix = r*66+col][32 ci][16B pad]
// RSTRIDE = 80 B/pix. b128 ops at stride 80: start banks 20*l mod 32 = 8 slots
// x 4 banks = all 32 banks, 8 accesses/bank over the 8 min clocks -> conflict-free.
#define TCOLS 66
#define RSTRIDE 80
#define LDS_BYTES (6*TCOLS*RSTRIDE)   // 31680 B

__device__ __forceinline__ unsigned int f2bf(float f) {
    unsigned int u = __builtin_bit_cast(unsigned int, f);
    u += 0x7fffu + ((u >> 16) & 1u);
    return u >> 16;
}

// packed f32x2 -> bf16x2 (RNE), 1 instruction
__device__ __forceinline__ unsigned int cvt_pk(float lo, float hi) {
    unsigned int r;
    asm("v_cvt_pk_bf16_f32 %0, %1, %2" : "=v"(r) : "v"(lo), "v"(hi));
    return r;
}

// tanh(x) = 1 - 2/(exp2(2*log2e*x)+1); exact at +/-inf, ~1e-7 abs err
__device__ __forceinline__ float fast_tanh(float x) {
    float e = __builtin_amdgcn_exp2f(x * 2.8853900817779268f);
    float r = __builtin_amdgcn_rcpf(e + 1.0f);
    return 1.0f - 2.0f * r;
}

// ---------------------------------------------------------------------------
// Pre-pass: weights (64,64,3,3) fp32 OIHW -> MFMA B-fragment order, bf16.
// flat elem idx = ((ks*4 + cf)*64 + lane)*8 + j
//   ks = 0..17: khw = ks>>1, ci-half = ks&1; cf = co quarter,
//   lane: co = cf*16 + (lane&15), ci = (ks&1)*32 + 8*(lane>>4) + j
// ---------------------------------------------------------------------------
__global__ void wxform(const float* __restrict__ w, unsigned short* __restrict__ ws) {
    int tid = blockIdx.x * 256 + threadIdx.x;
    if (tid >= 18*4*64*8) return;
    int j   = tid & 7;
    int l   = (tid >> 3) & 63;
    int cf  = (tid >> 9) & 3;
    int ks  = tid >> 11;
    int co  = cf*16 + (l & 15);
    int ci  = (ks & 1)*32 + ((l >> 4) << 3) + j;
    int khw = ks >> 1;               // kh*3+kw
    int kh  = khw / 3, kw = khw % 3;
    float v = w[co*(CI*9) + ci*9 + kh*3 + kw];
    ws[tid] = (unsigned short)f2bf(v);
}

// ---------------------------------------------------------------------------
// Main: implicit-GEMM conv + channel-min + tanh(tanh()).
// Two ci-half passes over a 31.7 KB LDS tile (r9-proven). This round:
// fit the 128-reg cap (single wfb buffer) and conflict-free b128 staging
// writes (quad-pair tasks, 6-deep load chain).
// ---------------------------------------------------------------------------
__global__ __launch_bounds__(256, 4)
void conv_min_tanh(const float* __restrict__ x,
                   const unsigned short* __restrict__ wfrag,
                   const float* __restrict__ bias,
                   float* __restrict__ out) {
    __shared__ __align__(16) char xs[LDS_BYTES];

    const int lane = threadIdx.x & 63;
    const int wv   = threadIdx.x >> 6;
    const int c0   = blockIdx.x * 64;   // ow base (0 or 64)
    const int r0   = blockIdx.y * 4;    // oh base
    const int b    = blockIdx.z;
    const float* xb = x + (size_t)b * CI * HW;

    const int lane_c = lane & 15;
    const int hi     = lane >> 4;

    const short8* wp = (const short8*)wfrag;
    const int orow = r0 + wv;
    const bool live = (orow < OH);       // wave-uniform

    f32x4 acc[4][4];
    #pragma unroll
    for (int m = 0; m < 4; ++m)
        #pragma unroll
        for (int cf = 0; cf < 4; ++cf)
            acc[m][cf] = (f32x4){0.f, 0.f, 0.f, 0.f};

    // single A-read base; all khw/m offsets are compile-time immediates
    const int abase = (wv*TCOLS + lane_c)*RSTRIDE + hi*16;

    #pragma unroll
    for (int cih = 0; cih < 2; ++cih) {
        // ---------------- stage half cih ----------------
        // main: 24 tasks = (row 0..5) x (ci quad-pair 0..3); lane = col.
        // Each lane: 8 plane loads -> 4 cvt_pk -> ONE ds_write_b128.
        #pragma unroll
        for (int i = 0; i < 6; ++i) {
            const int tsk = wv + 4*i;           // 0..23
            const int r   = tsk >> 2;           // 0..5
            const int p   = tsk & 3;            // quad-pair (8 ci)
            const int gr  = r0 + r;
            float f0=0.f,f1=0.f,f2=0.f,f3=0.f,f4=0.f,f5=0.f,f6=0.f,f7=0.f;
            if (gr < H) {                        // wave-uniform; zero-fill OOB
                const float* xp = xb + (size_t)(cih*32 + p*8)*HW + gr*W + c0 + lane;
                f0 = xp[0];    f1 = xp[HW];   f2 = xp[2*HW]; f3 = xp[3*HW];
                f4 = xp[4*HW]; f5 = xp[5*HW]; f6 = xp[6*HW]; f7 = xp[7*HW];
            }
            u32x4 pk;
            pk.x = cvt_pk(f0, f1); pk.y = cvt_pk(f2, f3);
            pk.z = cvt_pk(f4, f5); pk.w = cvt_pk(f6, f7);
            *(u32x4*)(xs + (r*TCOLS + lane)*RSTRIDE + p*16) = pk;
        }
        // halo cols 64,65: threads 0..47 -> (row 0..5) x (col 2) x (pair 4)
        if (threadIdx.x < 48) {
            const int r  = threadIdx.x >> 3;     // 0..5
            const int cc = (threadIdx.x >> 2) & 1;
            const int p  = threadIdx.x & 3;
            const int gr = r0 + r;
            const int gc = c0 + 64 + cc;
            float f0=0.f,f1=0.f,f2=0.f,f3=0.f,f4=0.f,f5=0.f,f6=0.f,f7=0.f;
            if (gr < H && gc < W) {              // zero-fill OOB
                const float* xq = xb + (size_t)(cih*32 + p*8)*HW + gr*W + gc;
                f0 = xq[0];    f1 = xq[HW];   f2 = xq[2*HW]; f3 = xq[3*HW];
                f4 = xq[4*HW]; f5 = xq[5*HW]; f6 = xq[6*HW]; f7 = xq[7*HW];
            }
            u32x4 pk;
            pk.x = cvt_pk(f0, f1); pk.y = cvt_pk(f2, f3);
            pk.z = cvt_pk(f4, f5); pk.w = cvt_pk(f6, f7);
            *(u32x4*)(xs + (r*TCOLS + 64 + cc)*RSTRIDE + p*16) = pk;
        }
        __syncthreads();

        // ---------------- compute half cih ----------------
        if (live) {
            #pragma unroll
            for (int khw = 0; khw < 9; ++khw) {
                short8 wfb[4];                   // single buffer: fits reg cap
                #pragma unroll
                for (int cf = 0; cf < 4; ++cf)
                    wfb[cf] = wp[((khw*2 + cih)*4 + cf)*64 + lane];
                const int kh = khw/3, kw = khw%3;
                #pragma unroll
                for (int m = 0; m < 4; ++m) {
                    const short8 av = *(const short8*)(
                        xs + abase + (kh*TCOLS + kw + m*16)*RSTRIDE);
                    const bf16x8 a = __builtin_bit_cast(bf16x8, av);
                    #pragma unroll
                    for (int cf = 0; cf < 4; ++cf)
                        acc[m][cf] = __builtin_amdgcn_mfma_f32_16x16x32_bf16(
                            a, __builtin_bit_cast(bf16x8, wfb[cf]), acc[m][cf], 0, 0, 0);
                }
            }
        }
        if (cih == 0) __syncthreads();   // all reads done before restage
    }

    if (!live) return;

    // ---- epilogue: +bias, min over 64 co, tanh(tanh()), store ----
    const float bs0 = bias[lane_c], bs1 = bias[16 + lane_c],
                bs2 = bias[32 + lane_c], bs3 = bias[48 + lane_c];
    float* outp = out + (b*OH + orow)*OW;
    #pragma unroll
    for (int m = 0; m < 4; ++m) {
        #pragma unroll
        for (int rg = 0; rg < 4; ++rg) {
            float v0 = fminf(fminf(acc[m][0][rg] + bs0, acc[m][1][rg] + bs1),
                             fminf(acc[m][2][rg] + bs2, acc[m][3][rg] + bs3));
            v0 = fminf(v0, __shfl_xor(v0, 1));
            v0 = fminf(v0, __shfl_xor(v0, 2));
            v0 = fminf(v0, __shfl_xor(v0, 4));
            v0 = fminf(v0, __shfl_xor(v0, 8));
            const float vt = fast_tanh(fast_tanh(v0));
            const int ocol = c0 + m*16 + hi*4 + rg;
            if (lane_c == 0 && ocol < OW) outp[ocol] = vt;
        }
    }
}

extern "C" void kernel_launch(void* const* d_in, const int* in_sizes, int n_in,
                              void* d_out, int out_size, void* d_ws, size_t ws_size,
                              hipStream_t stream) {
    const float* x    = (const float*)d_in[0];
    const float* w    = (const float*)d_in[1];
    const float* bias = (const float*)d_in[2];
    float* out        = (float*)d_out;
    unsigned short* wbuf = (unsigned short*)d_ws;   // needs 73728 B

    wxform<<<dim3(144), dim3(256), 0, stream>>>(w, wbuf);
    conv_min_tanh<<<dim3(2, 32, NB), dim3(256), 0, stream>>>(x, wbuf, bias, out);
}